// Round 12
// baseline (292.544 us; speedup 1.0000x reference)
//
#include <hip/hip_runtime.h>
#include <hip/hip_bf16.h>
#include <hip/hip_fp16.h>
#include <math.h>

// MoNet / GMMConv 2-layer GNN on MI355X (gfx950).
// R21 = R20 with the NT-load compile fix: __builtin_nontemporal_load
// requires a clang ext_vector pointer, not HIP_vector_type (uint4).
// Use v4u = uint ext_vector_type(4) for the gemm12 A-tile NT loads.
// R20 theory: NT hints on the single-use Z stream —
//   - z1 epilogue: NT stores for Z (100MB written once, read once) so the
//     stream doesn't evict hot x lines (z1 FETCH=88MB vs ~26MB cold).
//   - gemm12 A-tile staging: NT loads (single-use 115MB stream).
//   - W1t/G2pT/gx2e/rec keep normal caching (reused).
// Rest byte-identical to R18 (best, 283.3us): unpredicated 8-blocks +
// scalar tail, rank-from-hist, no-atomic fillrec (16B rec), LDS-param
// expf staging, pk_fma, fused gemm12, 1-kernel scan, no cold tails.

#define NF 128
#define NH 64
#define NC 16
#define Z1NODES 16
#define Z1CAP 448
#define E2NODES 16
#define E2CAP 448
#define GXST 160   // gx2e row stride in ushorts (144 cols + pad, 320B rows)

typedef __bf16 v8bf __attribute__((ext_vector_type(8)));
typedef float v4f __attribute__((ext_vector_type(4)));
typedef float v2f __attribute__((ext_vector_type(2)));
typedef uint v4u __attribute__((ext_vector_type(4)));

__device__ inline ushort f2bu(float x) {
  __hip_bfloat16 h = __float2bfloat16(x);
  return *(ushort*)&h;
}
__device__ inline v8bf ld_frag(const ushort* p) {
  uint4 u = *(const uint4*)p;
  return __builtin_bit_cast(v8bf, u);
}
__device__ inline v2f fma2(float w, v2f f, v2f a) {
  return __builtin_elementwise_fma((v2f){w, w}, f, a);
}

// ---- setup: hist+rank | cast_x | prep | bagg-init, by blockIdx range ----
__global__ __launch_bounds__(256) void setup_kernel(
    const int* __restrict__ col, const float* __restrict__ x,
    const float* __restrict__ g1w, const float* __restrict__ r1w,
    const float* __restrict__ g2w, const float* __restrict__ r2w,
    int* __restrict__ counts, int* __restrict__ rank,
    ushort* __restrict__ A1, ushort* __restrict__ W1t,
    ushort* __restrict__ G2pT, int* __restrict__ bagg,
    int E, int N, int bh, int bc, int bp) {
  const int b = blockIdx.x, t = threadIdx.x;
  if (b < bh) {                               // hist + rank
    int e = b * 256 + t;
    if (e < E) rank[e] = atomicAdd(&counts[col[e]], 1);
  } else if (b < bh + bc) {                   // cast_x
    int idx = (b - bh) * 256 + t;
    if (idx < N * 32) {
      int n = idx >> 5, c4 = idx & 31;
      float4 v = ((const float4*)x)[idx];
      ushort4 o;
      o.x = f2bu(v.x); o.y = f2bu(v.y); o.z = f2bu(v.z); o.w = f2bu(v.w);
      *(ushort4*)(A1 + (size_t)n * 1152 + 1024 + c4 * 4) = o;
    }
  } else if (b < bh + bc + bp) {              // prep
    int i = (b - bh - bc) * 256 + t;
    if (i < 64 * 1152) {
      int h = i / 1152, j = i % 1152;
      float v = (j < 1024) ? g1w[(size_t)(j & 127) * 512 + (j >> 7) * 64 + h]
                           : r1w[(size_t)(j - 1024) * 64 + h];
      W1t[i] = f2bu(v);
    } else {
      int i2 = i - 64 * 1152;
      if (i2 < 144 * 64) {
        int cp = i2 / 64, f = i2 % 64;
        float v;
        if (cp < 128) {
          int kq = cp >> 5, rem = cp & 31;
          int o = rem >> 1, k = kq * 2 + (rem & 1);
          v = g2w[(size_t)f * 128 + k * 16 + o];
        } else {
          v = r2w[(size_t)f * 16 + (cp - 128)];
        }
        G2pT[i2] = f2bu(v);
      }
    }
  } else {                                    // bagg init
    if (t < 64) bagg[t] = 0;
  }
}

// ---- scan: single kernel, parallel-aggregate lookback (NB <= 64) ----
__global__ __launch_bounds__(256) void scan_kernel(
    const int* __restrict__ counts, int* __restrict__ starts,
    int* __restrict__ bagg, int NB) {
  __shared__ int wsum[4];
  __shared__ int s_pre;
  const int t = threadIdx.x, lane = t & 63, wv = t >> 6;
  const int b = blockIdx.x;
  int4 v = ((const int4*)counts)[b * 256 + t];
  int tsum = v.x + v.y + v.z + v.w;
  int inc = tsum;
  #pragma unroll
  for (int off = 1; off < 64; off <<= 1) {
    int u = __shfl_up(inc, off, 64);
    if (lane >= off) inc += u;
  }
  if (lane == 63) wsum[wv] = inc;
  __syncthreads();
  int agg = wsum[0] + wsum[1] + wsum[2] + wsum[3];
  if (t == 0) atomicExch(&bagg[b], agg + 1);  // publish (value+1, 0 = unset)
  __threadfence();
  int pre = 0;
  if (wv == 0) {
    if (t < b) {
      int val;
      do { val = atomicAdd(&bagg[t], 0); } while (val == 0);
      pre = val - 1;
    }
    #pragma unroll
    for (int off = 32; off >= 1; off >>= 1) pre += __shfl_xor(pre, off, 64);
    if (lane == 0) s_pre = pre;
  }
  __syncthreads();
  int wpre = 0;
  for (int j = 0; j < wv; ++j) wpre += wsum[j];
  int excl = s_pre + wpre + inc - tsum;
  int4 o;
  o.x = excl; o.y = o.x + v.x; o.z = o.y + v.y; o.w = o.z + v.z;
  ((int4*)starts)[b * 256 + t] = o;
}

// ---- fillrec: NO atomic; one 16B scattered store per edge ----
__global__ __launch_bounds__(256) void fillrec_kernel(
    const int* __restrict__ row, const int* __restrict__ col,
    const int* __restrict__ rank, const int* __restrict__ starts,
    const float* __restrict__ eattr, uint4* __restrict__ rec, int E) {
  int e = blockIdx.x * 256 + threadIdx.x;
  if (e >= E) return;
  int pos = starts[col[e]] + rank[e];
  int r = row[e];
  float2 p = *(const float2*)(eattr + 2 * e);
  rec[pos] = make_uint4((uint)(r * 2304), __float_as_uint(p.x),
                        __float_as_uint(p.y), (uint)(r * 320));
}

// ======= z1: Z[n,k*128+f] = (1/deg) sum w_ek x_bf[r,f] =======
// Unpredicated 8-blocks + scalar tail; NT stores for Z.
__global__ __launch_bounds__(256) void z1_kernel(
    ushort* __restrict__ A1, const uint4* __restrict__ rec,
    const float* __restrict__ mu1, const float* __restrict__ sg1,
    const int* __restrict__ starts, int N) {
  __shared__ __align__(16) float lw[Z1CAP + 8][8];
  __shared__ int loff[Z1CAP + 8];
  __shared__ float prm[32];   // [0..7]=-0.5/s0^2, [8..15]=-0.5/s1^2,
                              // [16..23]=mu0, [24..31]=mu1
  const int t = threadIdx.x, lane = t & 63, wv = t >> 6;
  const int base = (int)blockIdx.x * Z1NODES;
  const int S = starts[base];
  const int cl = min(starts[base + Z1NODES] - S, Z1CAP);
  if (t < 8) {
    float s0 = sg1[2 * t], s1 = sg1[2 * t + 1];
    prm[t] = -0.5f / (1e-15f + s0 * s0);
    prm[8 + t] = -0.5f / (1e-15f + s1 * s1);
    prm[16 + t] = mu1[2 * t];
    prm[24 + t] = mu1[2 * t + 1];
  }
  __syncthreads();
  for (int i = t; i < cl; i += 256) {
    uint4 rr = rec[S + i];
    loff[i] = (int)rr.x;
    float p0 = __uint_as_float(rr.y), p1 = __uint_as_float(rr.z);
    float w[8];
    #pragma unroll
    for (int k = 0; k < 8; ++k) {
      float d0 = p0 - prm[16 + k], d1 = p1 - prm[24 + k];
      w[k] = __expf(fmaf(d0 * d0, prm[k], d1 * d1 * prm[8 + k]));
    }
    *(float4*)&lw[i][0] = make_float4(w[0], w[1], w[2], w[3]);
    *(float4*)&lw[i][4] = make_float4(w[4], w[5], w[6], w[7]);
  }
  if (t < 8) {                             // 8 zero-weight sentinels (safety)
    loff[cl + t] = 0;
    *(float4*)&lw[cl + t][0] = make_float4(0.f, 0.f, 0.f, 0.f);
    *(float4*)&lw[cl + t][4] = make_float4(0.f, 0.f, 0.f, 0.f);
  }
  __syncthreads();

  const char* xb = (const char*)(A1 + 1024) + (lane << 2);

  for (int i = 0; i < Z1NODES / 4; ++i) {
    const int n = base + wv * 4 + i;
    const int be = starts[n], ee = starts[n + 1];
    v2f A[8];
    #pragma unroll
    for (int k = 0; k < 8; ++k) A[k] = (v2f){0.f, 0.f};

    const int reRel = min(ee - S, cl);
    int q = min(be - S, cl);
    for (; q + 8 <= reRel; q += 8) {       // full blocks: no predication
      int off[8];
      #pragma unroll
      for (int u = 0; u < 8; ++u) off[u] = loff[q + u];
      uint g[8];
      #pragma unroll
      for (int u = 0; u < 8; ++u) g[u] = *(const uint*)(xb + off[u]);
      #pragma unroll
      for (int u = 0; u < 8; ++u) {
        float4 wl = *(float4*)&lw[q + u][0];
        float4 wh = *(float4*)&lw[q + u][4];
        v2f F;
        F.x = __uint_as_float(g[u] << 16);
        F.y = __uint_as_float(g[u] & 0xffff0000u);
        A[0] = fma2(wl.x, F, A[0]);
        A[1] = fma2(wl.y, F, A[1]);
        A[2] = fma2(wl.z, F, A[2]);
        A[3] = fma2(wl.w, F, A[3]);
        A[4] = fma2(wh.x, F, A[4]);
        A[5] = fma2(wh.y, F, A[5]);
        A[6] = fma2(wh.z, F, A[6]);
        A[7] = fma2(wh.w, F, A[7]);
      }
    }
    for (; q < reRel; ++q) {               // scalar tail (<8 edges)
      uint g = *(const uint*)(xb + loff[q]);
      float4 wl = *(float4*)&lw[q][0];
      float4 wh = *(float4*)&lw[q][4];
      v2f F;
      F.x = __uint_as_float(g << 16);
      F.y = __uint_as_float(g & 0xffff0000u);
      A[0] = fma2(wl.x, F, A[0]);
      A[1] = fma2(wl.y, F, A[1]);
      A[2] = fma2(wl.z, F, A[2]);
      A[3] = fma2(wl.w, F, A[3]);
      A[4] = fma2(wh.x, F, A[4]);
      A[5] = fma2(wh.y, F, A[5]);
      A[6] = fma2(wh.z, F, A[6]);
      A[7] = fma2(wh.w, F, A[7]);
    }
    const float inv = 1.f / fmaxf((float)(ee - be), 1.f);
    ushort* zr = A1 + (size_t)n * 1152;
    #pragma unroll
    for (int k = 0; k < 8; ++k) {
      uint pk = (uint)f2bu(A[k].x * inv) | ((uint)f2bu(A[k].y * inv) << 16);
      __builtin_nontemporal_store(pk, (uint*)(zr + k * 128 + 2 * lane));
    }
  }
}

// ---- gemm12: h = ELU(A1 @ W1t^T + b1) in LDS; gx2e = h @ G2pT^T ----
// A-tile staging uses NT loads (single-use 115MB stream), via v4u.
__global__ __launch_bounds__(256) void gemm12_kernel(
    const ushort* __restrict__ A1, const ushort* __restrict__ W1t,
    const float* __restrict__ b1, const ushort* __restrict__ G2pT,
    ushort* __restrict__ gx2e, int N) {
  __shared__ __align__(16) ushort As[2][64 * 32];
  __shared__ __align__(16) ushort Bs[2][64 * 32];
  __shared__ __align__(16) ushort Hs[64][72];   // padded: no bank wall
  const int t = threadIdx.x, lane = t & 63, wv = t >> 6;
  const int mfrag = lane & 15, quad = lane >> 4;
  const int m0 = (int)blockIdx.x * 64;
  const int st_r = t >> 2, st_c = (t & 3) * 8;
  const int st_o = st_r * 32 + st_c;
  const ushort* ag = A1 + (size_t)(m0 + st_r) * 1152 + st_c;
  const ushort* bg = W1t + (size_t)st_r * 1152 + st_c;

  {
    v4u a0 = __builtin_nontemporal_load((const v4u*)ag);
    v4u b0 = *(const v4u*)bg;
    *(v4u*)(&As[0][st_o]) = a0;
    *(v4u*)(&Bs[0][st_o]) = b0;
  }
  __syncthreads();

  v4f acc[4];
  #pragma unroll
  for (int ct = 0; ct < 4; ++ct) acc[ct] = (v4f){0.f, 0.f, 0.f, 0.f};

  for (int kc = 0; kc < 36; ++kc) {
    const int cb = kc & 1, nb = cb ^ 1;
    v4u an, bn;
    if (kc < 35) {
      an = __builtin_nontemporal_load((const v4u*)(ag + (kc + 1) * 32));
      bn = *(const v4u*)(bg + (kc + 1) * 32);
    }
    v8bf a = ld_frag(&As[cb][(wv * 16 + mfrag) * 32 + quad * 8]);
    #pragma unroll
    for (int ct = 0; ct < 4; ++ct) {
      v8bf b = ld_frag(&Bs[cb][(ct * 16 + mfrag) * 32 + quad * 8]);
      acc[ct] = __builtin_amdgcn_mfma_f32_16x16x32_bf16(a, b, acc[ct], 0, 0, 0);
    }
    if (kc < 35) {
      *(v4u*)(&As[nb][st_o]) = an;
      *(v4u*)(&Bs[nb][st_o]) = bn;
      __syncthreads();
    }
  }
  // epilogue 1: ELU -> Hs (LDS), no global h round-trip
  #pragma unroll
  for (int ct = 0; ct < 4; ++ct) {
    const int colh = ct * 16 + mfrag;
    const float bc = b1[colh];
    #pragma unroll
    for (int r = 0; r < 4; ++r) {
      float v = acc[ct][r] + bc;
      v = v > 0.f ? v : expm1f(v);
      Hs[wv * 16 + quad * 4 + r][colh] = f2bu(v);
    }
  }
  __syncthreads();

  // phase 2 (was gemm2a): gx2e = Hs @ G2pT^T
  v4f acc2[9];
  #pragma unroll
  for (int t9 = 0; t9 < 9; ++t9) acc2[t9] = (v4f){0.f, 0.f, 0.f, 0.f};
  const ushort* brow = G2pT + (size_t)mfrag * 64 + quad * 8;
  #pragma unroll
  for (int kc = 0; kc < 2; ++kc) {
    v8bf a = ld_frag(&Hs[wv * 16 + mfrag][quad * 8 + kc * 32]);
    #pragma unroll
    for (int t9 = 0; t9 < 9; ++t9) {
      v8bf b = ld_frag(brow + (size_t)t9 * 16 * 64 + kc * 32);
      acc2[t9] = __builtin_amdgcn_mfma_f32_16x16x32_bf16(a, b, acc2[t9], 0, 0, 0);
    }
  }
  #pragma unroll
  for (int t9 = 0; t9 < 9; ++t9) {
    #pragma unroll
    for (int r = 0; r < 4; ++r) {
      int node = m0 + wv * 16 + quad * 4 + r;
      if (node < N)
        gx2e[(size_t)node * GXST + t9 * 16 + mfrag] = f2bu(acc2[t9][r]);
    }
  }
}

// ==== edge2: out = lsm( (sum_e w.gx2e[r])/deg + root + b2 ) ====
// Unpredicated 8-blocks + scalar tail.
__global__ __launch_bounds__(256) void edge2_kernel(
    const ushort* __restrict__ gx2e, const uint4* __restrict__ rec,
    const float* __restrict__ mu2, const float* __restrict__ sg2,
    const int* __restrict__ starts, const float* __restrict__ b2,
    float* __restrict__ out, int N) {
  __shared__ __align__(16) float lw[E2CAP + 8][8];
  __shared__ int loff[E2CAP + 8];
  __shared__ float lb2[16];
  __shared__ float prm[32];
  const int t = threadIdx.x, lane = t & 63, wv = t >> 6;
  const int base = (int)blockIdx.x * E2NODES;
  const int S = starts[base];
  const int cl = min(starts[base + E2NODES] - S, E2CAP);
  if (t < 16) lb2[t] = b2[t];
  if (t < 8) {
    float s0 = sg2[2 * t], s1 = sg2[2 * t + 1];
    prm[t] = -0.5f / (1e-15f + s0 * s0);
    prm[8 + t] = -0.5f / (1e-15f + s1 * s1);
    prm[16 + t] = mu2[2 * t];
    prm[24 + t] = mu2[2 * t + 1];
  }
  __syncthreads();
  for (int i = t; i < cl; i += 256) {
    uint4 rr = rec[S + i];
    loff[i] = (int)rr.w;
    float p0 = __uint_as_float(rr.y), p1 = __uint_as_float(rr.z);
    float w[8];
    #pragma unroll
    for (int k = 0; k < 8; ++k) {
      float d0 = p0 - prm[16 + k], d1 = p1 - prm[24 + k];
      w[k] = __expf(fmaf(d0 * d0, prm[k], d1 * d1 * prm[8 + k]));
    }
    *(float4*)&lw[i][0] = make_float4(w[0], w[1], w[2], w[3]);
    *(float4*)&lw[i][4] = make_float4(w[4], w[5], w[6], w[7]);
  }
  if (t < 8) {                             // 8 zero-weight sentinels (safety)
    loff[cl + t] = 0;
    *(float4*)&lw[cl + t][0] = make_float4(0.f, 0.f, 0.f, 0.f);
    *(float4*)&lw[cl + t][4] = make_float4(0.f, 0.f, 0.f, 0.f);
  }
  __syncthreads();

  const int o = lane & 15, kq = lane >> 4;
  const char* gb = (const char*)gx2e + kq * 64 + o * 4;

  for (int i = 0; i < E2NODES / 4; ++i) {
    const int n = base + wv * 4 + i;
    if (n >= N) continue;
    const int be = starts[n], ee = starts[n + 1];
    v2f ACC = (v2f){0.f, 0.f};
    const int reRel = min(ee - S, cl);
    int q = min(be - S, cl);
    for (; q + 8 <= reRel; q += 8) {       // full blocks: no predication
      int off[8];
      #pragma unroll
      for (int u = 0; u < 8; ++u) off[u] = loff[q + u];
      uint g[8];
      #pragma unroll
      for (int u = 0; u < 8; ++u) g[u] = *(const uint*)(gb + off[u]);
      #pragma unroll
      for (int u = 0; u < 8; ++u) {
        v2f W = *(v2f*)&lw[q + u][kq * 2];
        v2f F;
        F.x = __uint_as_float(g[u] << 16);
        F.y = __uint_as_float(g[u] & 0xffff0000u);
        ACC = __builtin_elementwise_fma(W, F, ACC);
      }
    }
    for (; q < reRel; ++q) {               // scalar tail (<8 edges)
      uint g = *(const uint*)(gb + loff[q]);
      v2f W = *(v2f*)&lw[q][kq * 2];
      v2f F;
      F.x = __uint_as_float(g << 16);
      F.y = __uint_as_float(g & 0xffff0000u);
      ACC = __builtin_elementwise_fma(W, F, ACC);
    }
    float s = ACC.x + ACC.y;
    s += __shfl_xor(s, 16, 64);
    s += __shfl_xor(s, 32, 64);
    const float inv = 1.f / fmaxf((float)(ee - be), 1.f);
    ushort ru = *((const ushort*)gx2e + (size_t)n * GXST + 128 + o);
    float root = __uint_as_float(((uint)ru) << 16);
    float v = s * inv + root + lb2[o];
    float mx = v;
    #pragma unroll
    for (int off = 8; off >= 1; off >>= 1) mx = fmaxf(mx, __shfl_xor(mx, off, 64));
    float sm = __expf(v - mx);
    #pragma unroll
    for (int off = 8; off >= 1; off >>= 1) sm += __shfl_xor(sm, off, 64);
    if (kq == 0) out[(size_t)n * NC + o] = v - mx - __logf(sm);
  }
}

extern "C" void kernel_launch(void* const* d_in, const int* in_sizes, int n_in,
                              void* d_out, int out_size, void* d_ws, size_t ws_size,
                              hipStream_t stream) {
  const float* x     = (const float*)d_in[0];
  const int*   eidx  = (const int*)d_in[1];
  const float* eattr = (const float*)d_in[2];
  const float* g1w   = (const float*)d_in[3];
  const float* mu1   = (const float*)d_in[4];
  const float* sg1   = (const float*)d_in[5];
  const float* r1w   = (const float*)d_in[6];
  const float* b1    = (const float*)d_in[7];
  const float* g2w   = (const float*)d_in[8];
  const float* mu2   = (const float*)d_in[9];
  const float* sg2   = (const float*)d_in[10];
  const float* r2w   = (const float*)d_in[11];
  const float* b2    = (const float*)d_in[12];

  const int N = in_sizes[0] / NF;        // 50000
  const int E = in_sizes[1] / 2;         // 800000
  const int* row = eidx;
  const int* col = eidx + E;
  const int N2 = (N + 63) & ~63;         // 50048
  const int NP = (N + 1023) & ~1023;     // 50176
  const int NB = NP / 1024;              // 49 (must be <= 64 for scan_kernel)

  // layout: [rec | gx2e | A1 | W1t | G2pT | rank | counts | starts | bagg]
  char* wsb = (char*)d_ws;
  uint4* rec   = (uint4*)wsb;                              // E*16B (live to end)
  ushort* gx2e = (ushort*)(wsb + (size_t)E * 16);          // N2*320B
  ushort* A1   = gx2e + (size_t)N2 * GXST;                 // N2*1152 (Z1|x)
  ushort* W1t  = A1 + (size_t)N2 * 1152;                   // 64*1152
  ushort* G2pT = W1t + (size_t)64 * 1152;                  // 144*64
  int* rank    = (int*)(G2pT + (size_t)144 * 64);          // E
  int* counts  = rank + (size_t)E;                         // NP
  int* starts  = counts + NP;                              // NP
  int* bagg    = starts + NP;                              // 64

  const int bh = (E + 255) / 256;
  const int bc = (N * 32 + 255) / 256;
  const int bp = (64 * 1152 + 144 * 64 + 255) / 256;

  hipMemsetAsync(counts, 0, (size_t)NP * sizeof(int), stream);
  setup_kernel<<<bh + bc + bp + 1, 256, 0, stream>>>(
      col, x, g1w, r1w, g2w, r2w, counts, rank, A1, W1t, G2pT, bagg,
      E, N, bh, bc, bp);
  scan_kernel<<<NB, 256, 0, stream>>>(counts, starts, bagg, NB);
  fillrec_kernel<<<bh, 256, 0, stream>>>(row, col, rank, starts, eattr, rec, E);
  z1_kernel<<<N / Z1NODES, 256, 0, stream>>>(A1, rec, mu1, sg1, starts, N);
  gemm12_kernel<<<N2 / 64, 256, 0, stream>>>(A1, W1t, b1, G2pT, gx2e, N);
  edge2_kernel<<<(N + E2NODES - 1) / E2NODES, 256, 0, stream>>>(
      gx2e, rec, mu2, sg2, starts, b2, (float*)d_out, N);
}

// Round 13
// 283.099 us; speedup vs baseline: 1.0334x; 1.0334x over previous
//
#include <hip/hip_runtime.h>
#include <hip/hip_bf16.h>
#include <hip/hip_fp16.h>
#include <math.h>

// MoNet / GMMConv 2-layer GNN on MI355X (gfx950).
// R22 = R18 (best, 283.3us) + gemm12 LDS bank-conflict fix:
//   - As/Bs row stride 32 -> 40 ushorts (80B rows: 16B-aligned for b128,
//     bank-stride 20 words -> 2-way conflict = free, vs 8-way before).
//     Evidence: R21 counters showed gemm12 SQ_LDS_BANK_CONFLICT=2.27M
//     (11x z1's) — pre-existing in the [64][32] tile layout.
//   - LDS 42.5 -> 50.2KB, still 3 blocks/CU (occupancy unchanged).
// R20/R21 NT hints REVERTED: NT store evicted Z from L2/L3 and NT loads
// don't fill — gemm12 went ~28 -> 57us (VALUBusy 6%) paying raw HBM
// latency at 24% occupancy. Z's cache residency is gemm12's asset.
// Rest byte-identical to R18: unpredicated 8-blocks + scalar tail,
// rank-from-hist, no-atomic fillrec (16B rec), LDS-param expf staging,
// pk_fma, fused gemm12, 1-kernel scan, no cold tails.

#define NF 128
#define NH 64
#define NC 16
#define Z1NODES 16
#define Z1CAP 448
#define E2NODES 16
#define E2CAP 448
#define GXST 160   // gx2e row stride in ushorts (144 cols + pad, 320B rows)
#define ABST 40    // As/Bs row stride in ushorts (80B: aligned + 2-way banks)

typedef __bf16 v8bf __attribute__((ext_vector_type(8)));
typedef float v4f __attribute__((ext_vector_type(4)));
typedef float v2f __attribute__((ext_vector_type(2)));

__device__ inline ushort f2bu(float x) {
  __hip_bfloat16 h = __float2bfloat16(x);
  return *(ushort*)&h;
}
__device__ inline v8bf ld_frag(const ushort* p) {
  uint4 u = *(const uint4*)p;
  return __builtin_bit_cast(v8bf, u);
}
__device__ inline v2f fma2(float w, v2f f, v2f a) {
  return __builtin_elementwise_fma((v2f){w, w}, f, a);
}

// ---- setup: hist+rank | cast_x | prep | bagg-init, by blockIdx range ----
__global__ __launch_bounds__(256) void setup_kernel(
    const int* __restrict__ col, const float* __restrict__ x,
    const float* __restrict__ g1w, const float* __restrict__ r1w,
    const float* __restrict__ g2w, const float* __restrict__ r2w,
    int* __restrict__ counts, int* __restrict__ rank,
    ushort* __restrict__ A1, ushort* __restrict__ W1t,
    ushort* __restrict__ G2pT, int* __restrict__ bagg,
    int E, int N, int bh, int bc, int bp) {
  const int b = blockIdx.x, t = threadIdx.x;
  if (b < bh) {                               // hist + rank
    int e = b * 256 + t;
    if (e < E) rank[e] = atomicAdd(&counts[col[e]], 1);
  } else if (b < bh + bc) {                   // cast_x
    int idx = (b - bh) * 256 + t;
    if (idx < N * 32) {
      int n = idx >> 5, c4 = idx & 31;
      float4 v = ((const float4*)x)[idx];
      ushort4 o;
      o.x = f2bu(v.x); o.y = f2bu(v.y); o.z = f2bu(v.z); o.w = f2bu(v.w);
      *(ushort4*)(A1 + (size_t)n * 1152 + 1024 + c4 * 4) = o;
    }
  } else if (b < bh + bc + bp) {              // prep
    int i = (b - bh - bc) * 256 + t;
    if (i < 64 * 1152) {
      int h = i / 1152, j = i % 1152;
      float v = (j < 1024) ? g1w[(size_t)(j & 127) * 512 + (j >> 7) * 64 + h]
                           : r1w[(size_t)(j - 1024) * 64 + h];
      W1t[i] = f2bu(v);
    } else {
      int i2 = i - 64 * 1152;
      if (i2 < 144 * 64) {
        int cp = i2 / 64, f = i2 % 64;
        float v;
        if (cp < 128) {
          int kq = cp >> 5, rem = cp & 31;
          int o = rem >> 1, k = kq * 2 + (rem & 1);
          v = g2w[(size_t)f * 128 + k * 16 + o];
        } else {
          v = r2w[(size_t)f * 16 + (cp - 128)];
        }
        G2pT[i2] = f2bu(v);
      }
    }
  } else {                                    // bagg init
    if (t < 64) bagg[t] = 0;
  }
}

// ---- scan: single kernel, parallel-aggregate lookback (NB <= 64) ----
__global__ __launch_bounds__(256) void scan_kernel(
    const int* __restrict__ counts, int* __restrict__ starts,
    int* __restrict__ bagg, int NB) {
  __shared__ int wsum[4];
  __shared__ int s_pre;
  const int t = threadIdx.x, lane = t & 63, wv = t >> 6;
  const int b = blockIdx.x;
  int4 v = ((const int4*)counts)[b * 256 + t];
  int tsum = v.x + v.y + v.z + v.w;
  int inc = tsum;
  #pragma unroll
  for (int off = 1; off < 64; off <<= 1) {
    int u = __shfl_up(inc, off, 64);
    if (lane >= off) inc += u;
  }
  if (lane == 63) wsum[wv] = inc;
  __syncthreads();
  int agg = wsum[0] + wsum[1] + wsum[2] + wsum[3];
  if (t == 0) atomicExch(&bagg[b], agg + 1);  // publish (value+1, 0 = unset)
  __threadfence();
  int pre = 0;
  if (wv == 0) {
    if (t < b) {
      int val;
      do { val = atomicAdd(&bagg[t], 0); } while (val == 0);
      pre = val - 1;
    }
    #pragma unroll
    for (int off = 32; off >= 1; off >>= 1) pre += __shfl_xor(pre, off, 64);
    if (lane == 0) s_pre = pre;
  }
  __syncthreads();
  int wpre = 0;
  for (int j = 0; j < wv; ++j) wpre += wsum[j];
  int excl = s_pre + wpre + inc - tsum;
  int4 o;
  o.x = excl; o.y = o.x + v.x; o.z = o.y + v.y; o.w = o.z + v.z;
  ((int4*)starts)[b * 256 + t] = o;
}

// ---- fillrec: NO atomic; one 16B scattered store per edge ----
__global__ __launch_bounds__(256) void fillrec_kernel(
    const int* __restrict__ row, const int* __restrict__ col,
    const int* __restrict__ rank, const int* __restrict__ starts,
    const float* __restrict__ eattr, uint4* __restrict__ rec, int E) {
  int e = blockIdx.x * 256 + threadIdx.x;
  if (e >= E) return;
  int pos = starts[col[e]] + rank[e];
  int r = row[e];
  float2 p = *(const float2*)(eattr + 2 * e);
  rec[pos] = make_uint4((uint)(r * 2304), __float_as_uint(p.x),
                        __float_as_uint(p.y), (uint)(r * 320));
}

// ======= z1: Z[n,k*128+f] = (1/deg) sum w_ek x_bf[r,f] =======
// Unpredicated 8-blocks + scalar tail. Staging recomputes w1 (LDS prm).
__global__ __launch_bounds__(256) void z1_kernel(
    ushort* __restrict__ A1, const uint4* __restrict__ rec,
    const float* __restrict__ mu1, const float* __restrict__ sg1,
    const int* __restrict__ starts, int N) {
  __shared__ __align__(16) float lw[Z1CAP + 8][8];
  __shared__ int loff[Z1CAP + 8];
  __shared__ float prm[32];   // [0..7]=-0.5/s0^2, [8..15]=-0.5/s1^2,
                              // [16..23]=mu0, [24..31]=mu1
  const int t = threadIdx.x, lane = t & 63, wv = t >> 6;
  const int base = (int)blockIdx.x * Z1NODES;
  const int S = starts[base];
  const int cl = min(starts[base + Z1NODES] - S, Z1CAP);
  if (t < 8) {
    float s0 = sg1[2 * t], s1 = sg1[2 * t + 1];
    prm[t] = -0.5f / (1e-15f + s0 * s0);
    prm[8 + t] = -0.5f / (1e-15f + s1 * s1);
    prm[16 + t] = mu1[2 * t];
    prm[24 + t] = mu1[2 * t + 1];
  }
  __syncthreads();
  for (int i = t; i < cl; i += 256) {
    uint4 rr = rec[S + i];
    loff[i] = (int)rr.x;
    float p0 = __uint_as_float(rr.y), p1 = __uint_as_float(rr.z);
    float w[8];
    #pragma unroll
    for (int k = 0; k < 8; ++k) {
      float d0 = p0 - prm[16 + k], d1 = p1 - prm[24 + k];
      w[k] = __expf(fmaf(d0 * d0, prm[k], d1 * d1 * prm[8 + k]));
    }
    *(float4*)&lw[i][0] = make_float4(w[0], w[1], w[2], w[3]);
    *(float4*)&lw[i][4] = make_float4(w[4], w[5], w[6], w[7]);
  }
  if (t < 8) {                             // 8 zero-weight sentinels (safety)
    loff[cl + t] = 0;
    *(float4*)&lw[cl + t][0] = make_float4(0.f, 0.f, 0.f, 0.f);
    *(float4*)&lw[cl + t][4] = make_float4(0.f, 0.f, 0.f, 0.f);
  }
  __syncthreads();

  const char* xb = (const char*)(A1 + 1024) + (lane << 2);

  for (int i = 0; i < Z1NODES / 4; ++i) {
    const int n = base + wv * 4 + i;
    const int be = starts[n], ee = starts[n + 1];
    v2f A[8];
    #pragma unroll
    for (int k = 0; k < 8; ++k) A[k] = (v2f){0.f, 0.f};

    const int reRel = min(ee - S, cl);
    int q = min(be - S, cl);
    for (; q + 8 <= reRel; q += 8) {       // full blocks: no predication
      int off[8];
      #pragma unroll
      for (int u = 0; u < 8; ++u) off[u] = loff[q + u];
      uint g[8];
      #pragma unroll
      for (int u = 0; u < 8; ++u) g[u] = *(const uint*)(xb + off[u]);
      #pragma unroll
      for (int u = 0; u < 8; ++u) {
        float4 wl = *(float4*)&lw[q + u][0];
        float4 wh = *(float4*)&lw[q + u][4];
        v2f F;
        F.x = __uint_as_float(g[u] << 16);
        F.y = __uint_as_float(g[u] & 0xffff0000u);
        A[0] = fma2(wl.x, F, A[0]);
        A[1] = fma2(wl.y, F, A[1]);
        A[2] = fma2(wl.z, F, A[2]);
        A[3] = fma2(wl.w, F, A[3]);
        A[4] = fma2(wh.x, F, A[4]);
        A[5] = fma2(wh.y, F, A[5]);
        A[6] = fma2(wh.z, F, A[6]);
        A[7] = fma2(wh.w, F, A[7]);
      }
    }
    for (; q < reRel; ++q) {               // scalar tail (<8 edges)
      uint g = *(const uint*)(xb + loff[q]);
      float4 wl = *(float4*)&lw[q][0];
      float4 wh = *(float4*)&lw[q][4];
      v2f F;
      F.x = __uint_as_float(g << 16);
      F.y = __uint_as_float(g & 0xffff0000u);
      A[0] = fma2(wl.x, F, A[0]);
      A[1] = fma2(wl.y, F, A[1]);
      A[2] = fma2(wl.z, F, A[2]);
      A[3] = fma2(wl.w, F, A[3]);
      A[4] = fma2(wh.x, F, A[4]);
      A[5] = fma2(wh.y, F, A[5]);
      A[6] = fma2(wh.z, F, A[6]);
      A[7] = fma2(wh.w, F, A[7]);
    }
    const float inv = 1.f / fmaxf((float)(ee - be), 1.f);
    ushort* zr = A1 + (size_t)n * 1152;
    #pragma unroll
    for (int k = 0; k < 8; ++k) {
      uint pk = (uint)f2bu(A[k].x * inv) | ((uint)f2bu(A[k].y * inv) << 16);
      *(uint*)(zr + k * 128 + 2 * lane) = pk;
    }
  }
}

// ---- gemm12: h = ELU(A1 @ W1t^T + b1) in LDS; gx2e = h @ G2pT^T ----
// As/Bs stride 40 (80B rows): 2-way banks (free) vs 8-way at stride 32.
__global__ __launch_bounds__(256) void gemm12_kernel(
    const ushort* __restrict__ A1, const ushort* __restrict__ W1t,
    const float* __restrict__ b1, const ushort* __restrict__ G2pT,
    ushort* __restrict__ gx2e, int N) {
  __shared__ __align__(16) ushort As[2][64 * ABST];
  __shared__ __align__(16) ushort Bs[2][64 * ABST];
  __shared__ __align__(16) ushort Hs[64][72];   // padded: no bank wall
  const int t = threadIdx.x, lane = t & 63, wv = t >> 6;
  const int mfrag = lane & 15, quad = lane >> 4;
  const int m0 = (int)blockIdx.x * 64;
  const int st_r = t >> 2, st_c = (t & 3) * 8;
  const int st_o = st_r * ABST + st_c;
  const ushort* ag = A1 + (size_t)(m0 + st_r) * 1152 + st_c;
  const ushort* bg = W1t + (size_t)st_r * 1152 + st_c;

  {
    uint4 a0 = *(const uint4*)ag;
    uint4 b0 = *(const uint4*)bg;
    *(uint4*)(&As[0][st_o]) = a0;
    *(uint4*)(&Bs[0][st_o]) = b0;
  }
  __syncthreads();

  v4f acc[4];
  #pragma unroll
  for (int ct = 0; ct < 4; ++ct) acc[ct] = (v4f){0.f, 0.f, 0.f, 0.f};

  for (int kc = 0; kc < 36; ++kc) {
    const int cb = kc & 1, nb = cb ^ 1;
    uint4 an, bn;
    if (kc < 35) {
      an = *(const uint4*)(ag + (kc + 1) * 32);
      bn = *(const uint4*)(bg + (kc + 1) * 32);
    }
    v8bf a = ld_frag(&As[cb][(wv * 16 + mfrag) * ABST + quad * 8]);
    #pragma unroll
    for (int ct = 0; ct < 4; ++ct) {
      v8bf b = ld_frag(&Bs[cb][(ct * 16 + mfrag) * ABST + quad * 8]);
      acc[ct] = __builtin_amdgcn_mfma_f32_16x16x32_bf16(a, b, acc[ct], 0, 0, 0);
    }
    if (kc < 35) {
      *(uint4*)(&As[nb][st_o]) = an;
      *(uint4*)(&Bs[nb][st_o]) = bn;
      __syncthreads();
    }
  }
  // epilogue 1: ELU -> Hs (LDS), no global h round-trip
  #pragma unroll
  for (int ct = 0; ct < 4; ++ct) {
    const int colh = ct * 16 + mfrag;
    const float bc = b1[colh];
    #pragma unroll
    for (int r = 0; r < 4; ++r) {
      float v = acc[ct][r] + bc;
      v = v > 0.f ? v : expm1f(v);
      Hs[wv * 16 + quad * 4 + r][colh] = f2bu(v);
    }
  }
  __syncthreads();

  // phase 2 (was gemm2a): gx2e = Hs @ G2pT^T
  v4f acc2[9];
  #pragma unroll
  for (int t9 = 0; t9 < 9; ++t9) acc2[t9] = (v4f){0.f, 0.f, 0.f, 0.f};
  const ushort* brow = G2pT + (size_t)mfrag * 64 + quad * 8;
  #pragma unroll
  for (int kc = 0; kc < 2; ++kc) {
    v8bf a = ld_frag(&Hs[wv * 16 + mfrag][quad * 8 + kc * 32]);
    #pragma unroll
    for (int t9 = 0; t9 < 9; ++t9) {
      v8bf b = ld_frag(brow + (size_t)t9 * 16 * 64 + kc * 32);
      acc2[t9] = __builtin_amdgcn_mfma_f32_16x16x32_bf16(a, b, acc2[t9], 0, 0, 0);
    }
  }
  #pragma unroll
  for (int t9 = 0; t9 < 9; ++t9) {
    #pragma unroll
    for (int r = 0; r < 4; ++r) {
      int node = m0 + wv * 16 + quad * 4 + r;
      if (node < N)
        gx2e[(size_t)node * GXST + t9 * 16 + mfrag] = f2bu(acc2[t9][r]);
    }
  }
}

// ==== edge2: out = lsm( (sum_e w.gx2e[r])/deg + root + b2 ) ====
// Unpredicated 8-blocks + scalar tail.
__global__ __launch_bounds__(256) void edge2_kernel(
    const ushort* __restrict__ gx2e, const uint4* __restrict__ rec,
    const float* __restrict__ mu2, const float* __restrict__ sg2,
    const int* __restrict__ starts, const float* __restrict__ b2,
    float* __restrict__ out, int N) {
  __shared__ __align__(16) float lw[E2CAP + 8][8];
  __shared__ int loff[E2CAP + 8];
  __shared__ float lb2[16];
  __shared__ float prm[32];
  const int t = threadIdx.x, lane = t & 63, wv = t >> 6;
  const int base = (int)blockIdx.x * E2NODES;
  const int S = starts[base];
  const int cl = min(starts[base + E2NODES] - S, E2CAP);
  if (t < 16) lb2[t] = b2[t];
  if (t < 8) {
    float s0 = sg2[2 * t], s1 = sg2[2 * t + 1];
    prm[t] = -0.5f / (1e-15f + s0 * s0);
    prm[8 + t] = -0.5f / (1e-15f + s1 * s1);
    prm[16 + t] = mu2[2 * t];
    prm[24 + t] = mu2[2 * t + 1];
  }
  __syncthreads();
  for (int i = t; i < cl; i += 256) {
    uint4 rr = rec[S + i];
    loff[i] = (int)rr.w;
    float p0 = __uint_as_float(rr.y), p1 = __uint_as_float(rr.z);
    float w[8];
    #pragma unroll
    for (int k = 0; k < 8; ++k) {
      float d0 = p0 - prm[16 + k], d1 = p1 - prm[24 + k];
      w[k] = __expf(fmaf(d0 * d0, prm[k], d1 * d1 * prm[8 + k]));
    }
    *(float4*)&lw[i][0] = make_float4(w[0], w[1], w[2], w[3]);
    *(float4*)&lw[i][4] = make_float4(w[4], w[5], w[6], w[7]);
  }
  if (t < 8) {                             // 8 zero-weight sentinels (safety)
    loff[cl + t] = 0;
    *(float4*)&lw[cl + t][0] = make_float4(0.f, 0.f, 0.f, 0.f);
    *(float4*)&lw[cl + t][4] = make_float4(0.f, 0.f, 0.f, 0.f);
  }
  __syncthreads();

  const int o = lane & 15, kq = lane >> 4;
  const char* gb = (const char*)gx2e + kq * 64 + o * 4;

  for (int i = 0; i < E2NODES / 4; ++i) {
    const int n = base + wv * 4 + i;
    if (n >= N) continue;
    const int be = starts[n], ee = starts[n + 1];
    v2f ACC = (v2f){0.f, 0.f};
    const int reRel = min(ee - S, cl);
    int q = min(be - S, cl);
    for (; q + 8 <= reRel; q += 8) {       // full blocks: no predication
      int off[8];
      #pragma unroll
      for (int u = 0; u < 8; ++u) off[u] = loff[q + u];
      uint g[8];
      #pragma unroll
      for (int u = 0; u < 8; ++u) g[u] = *(const uint*)(gb + off[u]);
      #pragma unroll
      for (int u = 0; u < 8; ++u) {
        v2f W = *(v2f*)&lw[q + u][kq * 2];
        v2f F;
        F.x = __uint_as_float(g[u] << 16);
        F.y = __uint_as_float(g[u] & 0xffff0000u);
        ACC = __builtin_elementwise_fma(W, F, ACC);
      }
    }
    for (; q < reRel; ++q) {               // scalar tail (<8 edges)
      uint g = *(const uint*)(gb + loff[q]);
      v2f W = *(v2f*)&lw[q][kq * 2];
      v2f F;
      F.x = __uint_as_float(g << 16);
      F.y = __uint_as_float(g & 0xffff0000u);
      ACC = __builtin_elementwise_fma(W, F, ACC);
    }
    float s = ACC.x + ACC.y;
    s += __shfl_xor(s, 16, 64);
    s += __shfl_xor(s, 32, 64);
    const float inv = 1.f / fmaxf((float)(ee - be), 1.f);
    ushort ru = *((const ushort*)gx2e + (size_t)n * GXST + 128 + o);
    float root = __uint_as_float(((uint)ru) << 16);
    float v = s * inv + root + lb2[o];
    float mx = v;
    #pragma unroll
    for (int off = 8; off >= 1; off >>= 1) mx = fmaxf(mx, __shfl_xor(mx, off, 64));
    float sm = __expf(v - mx);
    #pragma unroll
    for (int off = 8; off >= 1; off >>= 1) sm += __shfl_xor(sm, off, 64);
    if (kq == 0) out[(size_t)n * NC + o] = v - mx - __logf(sm);
  }
}

extern "C" void kernel_launch(void* const* d_in, const int* in_sizes, int n_in,
                              void* d_out, int out_size, void* d_ws, size_t ws_size,
                              hipStream_t stream) {
  const float* x     = (const float*)d_in[0];
  const int*   eidx  = (const int*)d_in[1];
  const float* eattr = (const float*)d_in[2];
  const float* g1w   = (const float*)d_in[3];
  const float* mu1   = (const float*)d_in[4];
  const float* sg1   = (const float*)d_in[5];
  const float* r1w   = (const float*)d_in[6];
  const float* b1    = (const float*)d_in[7];
  const float* g2w   = (const float*)d_in[8];
  const float* mu2   = (const float*)d_in[9];
  const float* sg2   = (const float*)d_in[10];
  const float* r2w   = (const float*)d_in[11];
  const float* b2    = (const float*)d_in[12];

  const int N = in_sizes[0] / NF;        // 50000
  const int E = in_sizes[1] / 2;         // 800000
  const int* row = eidx;
  const int* col = eidx + E;
  const int N2 = (N + 63) & ~63;         // 50048
  const int NP = (N + 1023) & ~1023;     // 50176
  const int NB = NP / 1024;              // 49 (must be <= 64 for scan_kernel)

  // layout: [rec | gx2e | A1 | W1t | G2pT | rank | counts | starts | bagg]
  char* wsb = (char*)d_ws;
  uint4* rec   = (uint4*)wsb;                              // E*16B (live to end)
  ushort* gx2e = (ushort*)(wsb + (size_t)E * 16);          // N2*320B
  ushort* A1   = gx2e + (size_t)N2 * GXST;                 // N2*1152 (Z1|x)
  ushort* W1t  = A1 + (size_t)N2 * 1152;                   // 64*1152
  ushort* G2pT = W1t + (size_t)64 * 1152;                  // 144*64
  int* rank    = (int*)(G2pT + (size_t)144 * 64);          // E
  int* counts  = rank + (size_t)E;                         // NP
  int* starts  = counts + NP;                              // NP
  int* bagg    = starts + NP;                              // 64

  const int bh = (E + 255) / 256;
  const int bc = (N * 32 + 255) / 256;
  const int bp = (64 * 1152 + 144 * 64 + 255) / 256;

  hipMemsetAsync(counts, 0, (size_t)NP * sizeof(int), stream);
  setup_kernel<<<bh + bc + bp + 1, 256, 0, stream>>>(
      col, x, g1w, r1w, g2w, r2w, counts, rank, A1, W1t, G2pT, bagg,
      E, N, bh, bc, bp);
  scan_kernel<<<NB, 256, 0, stream>>>(counts, starts, bagg, NB);
  fillrec_kernel<<<bh, 256, 0, stream>>>(row, col, rank, starts, eattr, rec, E);
  z1_kernel<<<N / Z1NODES, 256, 0, stream>>>(A1, rec, mu1, sg1, starts, N);
  gemm12_kernel<<<N2 / 64, 256, 0, stream>>>(A1, W1t, b1, G2pT, gx2e, N);
  edge2_kernel<<<(N + E2NODES - 1) / E2NODES, 256, 0, stream>>>(
      gx2e, rec, mu2, sg2, starts, b2, (float*)d_out, N);
}

// Round 14
// 272.477 us; speedup vs baseline: 1.0736x; 1.0390x over previous
//
#include <hip/hip_runtime.h>
#include <hip/hip_bf16.h>
#include <hip/hip_fp16.h>
#include <math.h>

// MoNet / GMMConv 2-layer GNN on MI355X (gfx950).
// R23 = R22 (best, 283.1us) + byte-shaving package (no occupancy cost):
//   - rec 16B -> 8B: {row:int, p01:2xf16}; offsets r*2304 / r*320
//     recomputed in staging (1 mul, ~1 edge/thread). f16 attr is
//     precision-safe (R10-R13 used f16 WEIGHTS, same absmax 0.03125).
//     Halves fillrec's scattered store payload; -6.4MB fetch in z1 AND
//     edge2 staging.
//   - setup packs rc[e]=(rank<<16)|col (rank<64, col<65536); fillrec
//     reads one word instead of two (-3.2MB).
// Rest byte-identical to R22: ABST=40 gemm12 tiles, unpredicated
// 8-blocks + scalar tail, no-atomic fillrec, LDS-param expf staging,
// pk_fma, fused gemm12, 1-kernel scan, no cold tails.

#define NF 128
#define NH 64
#define NC 16
#define Z1NODES 16
#define Z1CAP 448
#define E2NODES 16
#define E2CAP 448
#define GXST 160   // gx2e row stride in ushorts (144 cols + pad, 320B rows)
#define ABST 40    // As/Bs row stride in ushorts (80B: aligned + 2-way banks)

typedef __bf16 v8bf __attribute__((ext_vector_type(8)));
typedef float v4f __attribute__((ext_vector_type(4)));
typedef float v2f __attribute__((ext_vector_type(2)));

__device__ inline ushort f2bu(float x) {
  __hip_bfloat16 h = __float2bfloat16(x);
  return *(ushort*)&h;
}
__device__ inline uint packh2(float a, float b) {
  __half ha = __float2half_rn(a), hb = __float2half_rn(b);
  return (uint)(*(ushort*)&ha) | ((uint)(*(ushort*)&hb) << 16);
}
__device__ inline float2 unph2(uint u) {
  ushort a = (ushort)(u & 0xffff), b = (ushort)(u >> 16);
  return make_float2(__half2float(*(__half*)&a), __half2float(*(__half*)&b));
}
__device__ inline v8bf ld_frag(const ushort* p) {
  uint4 u = *(const uint4*)p;
  return __builtin_bit_cast(v8bf, u);
}
__device__ inline v2f fma2(float w, v2f f, v2f a) {
  return __builtin_elementwise_fma((v2f){w, w}, f, a);
}

// ---- setup: hist+rc | cast_x | prep | bagg-init, by blockIdx range ----
__global__ __launch_bounds__(256) void setup_kernel(
    const int* __restrict__ col, const float* __restrict__ x,
    const float* __restrict__ g1w, const float* __restrict__ r1w,
    const float* __restrict__ g2w, const float* __restrict__ r2w,
    int* __restrict__ counts, int* __restrict__ rc,
    ushort* __restrict__ A1, ushort* __restrict__ W1t,
    ushort* __restrict__ G2pT, int* __restrict__ bagg,
    int E, int N, int bh, int bc, int bp) {
  const int b = blockIdx.x, t = threadIdx.x;
  if (b < bh) {                               // hist + packed rank|col
    int e = b * 256 + t;
    if (e < E) {
      int c = col[e];
      int rk = atomicAdd(&counts[c], 1);
      rc[e] = (rk << 16) | c;                 // rank<64, col<65536
    }
  } else if (b < bh + bc) {                   // cast_x
    int idx = (b - bh) * 256 + t;
    if (idx < N * 32) {
      int n = idx >> 5, c4 = idx & 31;
      float4 v = ((const float4*)x)[idx];
      ushort4 o;
      o.x = f2bu(v.x); o.y = f2bu(v.y); o.z = f2bu(v.z); o.w = f2bu(v.w);
      *(ushort4*)(A1 + (size_t)n * 1152 + 1024 + c4 * 4) = o;
    }
  } else if (b < bh + bc + bp) {              // prep
    int i = (b - bh - bc) * 256 + t;
    if (i < 64 * 1152) {
      int h = i / 1152, j = i % 1152;
      float v = (j < 1024) ? g1w[(size_t)(j & 127) * 512 + (j >> 7) * 64 + h]
                           : r1w[(size_t)(j - 1024) * 64 + h];
      W1t[i] = f2bu(v);
    } else {
      int i2 = i - 64 * 1152;
      if (i2 < 144 * 64) {
        int cp = i2 / 64, f = i2 % 64;
        float v;
        if (cp < 128) {
          int kq = cp >> 5, rem = cp & 31;
          int o = rem >> 1, k = kq * 2 + (rem & 1);
          v = g2w[(size_t)f * 128 + k * 16 + o];
        } else {
          v = r2w[(size_t)f * 16 + (cp - 128)];
        }
        G2pT[i2] = f2bu(v);
      }
    }
  } else {                                    // bagg init
    if (t < 64) bagg[t] = 0;
  }
}

// ---- scan: single kernel, parallel-aggregate lookback (NB <= 64) ----
__global__ __launch_bounds__(256) void scan_kernel(
    const int* __restrict__ counts, int* __restrict__ starts,
    int* __restrict__ bagg, int NB) {
  __shared__ int wsum[4];
  __shared__ int s_pre;
  const int t = threadIdx.x, lane = t & 63, wv = t >> 6;
  const int b = blockIdx.x;
  int4 v = ((const int4*)counts)[b * 256 + t];
  int tsum = v.x + v.y + v.z + v.w;
  int inc = tsum;
  #pragma unroll
  for (int off = 1; off < 64; off <<= 1) {
    int u = __shfl_up(inc, off, 64);
    if (lane >= off) inc += u;
  }
  if (lane == 63) wsum[wv] = inc;
  __syncthreads();
  int agg = wsum[0] + wsum[1] + wsum[2] + wsum[3];
  if (t == 0) atomicExch(&bagg[b], agg + 1);  // publish (value+1, 0 = unset)
  __threadfence();
  int pre = 0;
  if (wv == 0) {
    if (t < b) {
      int val;
      do { val = atomicAdd(&bagg[t], 0); } while (val == 0);
      pre = val - 1;
    }
    #pragma unroll
    for (int off = 32; off >= 1; off >>= 1) pre += __shfl_xor(pre, off, 64);
    if (lane == 0) s_pre = pre;
  }
  __syncthreads();
  int wpre = 0;
  for (int j = 0; j < wv; ++j) wpre += wsum[j];
  int excl = s_pre + wpre + inc - tsum;
  int4 o;
  o.x = excl; o.y = o.x + v.x; o.z = o.y + v.y; o.w = o.z + v.z;
  ((int4*)starts)[b * 256 + t] = o;
}

// ---- fillrec: NO atomic; one 8B scattered store per edge ----
__global__ __launch_bounds__(256) void fillrec_kernel(
    const int* __restrict__ row, const int* __restrict__ rc,
    const int* __restrict__ starts, const float* __restrict__ eattr,
    uint2* __restrict__ rec, int E) {
  int e = blockIdx.x * 256 + threadIdx.x;
  if (e >= E) return;
  int rc_ = rc[e];
  int pos = starts[rc_ & 0xffff] + (rc_ >> 16);
  int r = row[e];
  float2 p = *(const float2*)(eattr + 2 * e);
  rec[pos] = make_uint2((uint)r, packh2(p.x, p.y));
}

// ======= z1: Z[n,k*128+f] = (1/deg) sum w_ek x_bf[r,f] =======
// Unpredicated 8-blocks + scalar tail. Staging recomputes w1 (LDS prm).
__global__ __launch_bounds__(256) void z1_kernel(
    ushort* __restrict__ A1, const uint2* __restrict__ rec,
    const float* __restrict__ mu1, const float* __restrict__ sg1,
    const int* __restrict__ starts, int N) {
  __shared__ __align__(16) float lw[Z1CAP + 8][8];
  __shared__ int loff[Z1CAP + 8];
  __shared__ float prm[32];   // [0..7]=-0.5/s0^2, [8..15]=-0.5/s1^2,
                              // [16..23]=mu0, [24..31]=mu1
  const int t = threadIdx.x, lane = t & 63, wv = t >> 6;
  const int base = (int)blockIdx.x * Z1NODES;
  const int S = starts[base];
  const int cl = min(starts[base + Z1NODES] - S, Z1CAP);
  if (t < 8) {
    float s0 = sg1[2 * t], s1 = sg1[2 * t + 1];
    prm[t] = -0.5f / (1e-15f + s0 * s0);
    prm[8 + t] = -0.5f / (1e-15f + s1 * s1);
    prm[16 + t] = mu1[2 * t];
    prm[24 + t] = mu1[2 * t + 1];
  }
  __syncthreads();
  for (int i = t; i < cl; i += 256) {
    uint2 rr = rec[S + i];
    loff[i] = (int)rr.x * 2304;
    float2 p = unph2(rr.y);
    float w[8];
    #pragma unroll
    for (int k = 0; k < 8; ++k) {
      float d0 = p.x - prm[16 + k], d1 = p.y - prm[24 + k];
      w[k] = __expf(fmaf(d0 * d0, prm[k], d1 * d1 * prm[8 + k]));
    }
    *(float4*)&lw[i][0] = make_float4(w[0], w[1], w[2], w[3]);
    *(float4*)&lw[i][4] = make_float4(w[4], w[5], w[6], w[7]);
  }
  if (t < 8) {                             // 8 zero-weight sentinels (safety)
    loff[cl + t] = 0;
    *(float4*)&lw[cl + t][0] = make_float4(0.f, 0.f, 0.f, 0.f);
    *(float4*)&lw[cl + t][4] = make_float4(0.f, 0.f, 0.f, 0.f);
  }
  __syncthreads();

  const char* xb = (const char*)(A1 + 1024) + (lane << 2);

  for (int i = 0; i < Z1NODES / 4; ++i) {
    const int n = base + wv * 4 + i;
    const int be = starts[n], ee = starts[n + 1];
    v2f A[8];
    #pragma unroll
    for (int k = 0; k < 8; ++k) A[k] = (v2f){0.f, 0.f};

    const int reRel = min(ee - S, cl);
    int q = min(be - S, cl);
    for (; q + 8 <= reRel; q += 8) {       // full blocks: no predication
      int off[8];
      #pragma unroll
      for (int u = 0; u < 8; ++u) off[u] = loff[q + u];
      uint g[8];
      #pragma unroll
      for (int u = 0; u < 8; ++u) g[u] = *(const uint*)(xb + off[u]);
      #pragma unroll
      for (int u = 0; u < 8; ++u) {
        float4 wl = *(float4*)&lw[q + u][0];
        float4 wh = *(float4*)&lw[q + u][4];
        v2f F;
        F.x = __uint_as_float(g[u] << 16);
        F.y = __uint_as_float(g[u] & 0xffff0000u);
        A[0] = fma2(wl.x, F, A[0]);
        A[1] = fma2(wl.y, F, A[1]);
        A[2] = fma2(wl.z, F, A[2]);
        A[3] = fma2(wl.w, F, A[3]);
        A[4] = fma2(wh.x, F, A[4]);
        A[5] = fma2(wh.y, F, A[5]);
        A[6] = fma2(wh.z, F, A[6]);
        A[7] = fma2(wh.w, F, A[7]);
      }
    }
    for (; q < reRel; ++q) {               // scalar tail (<8 edges)
      uint g = *(const uint*)(xb + loff[q]);
      float4 wl = *(float4*)&lw[q][0];
      float4 wh = *(float4*)&lw[q][4];
      v2f F;
      F.x = __uint_as_float(g << 16);
      F.y = __uint_as_float(g & 0xffff0000u);
      A[0] = fma2(wl.x, F, A[0]);
      A[1] = fma2(wl.y, F, A[1]);
      A[2] = fma2(wl.z, F, A[2]);
      A[3] = fma2(wl.w, F, A[3]);
      A[4] = fma2(wh.x, F, A[4]);
      A[5] = fma2(wh.y, F, A[5]);
      A[6] = fma2(wh.z, F, A[6]);
      A[7] = fma2(wh.w, F, A[7]);
    }
    const float inv = 1.f / fmaxf((float)(ee - be), 1.f);
    ushort* zr = A1 + (size_t)n * 1152;
    #pragma unroll
    for (int k = 0; k < 8; ++k) {
      uint pk = (uint)f2bu(A[k].x * inv) | ((uint)f2bu(A[k].y * inv) << 16);
      *(uint*)(zr + k * 128 + 2 * lane) = pk;
    }
  }
}

// ---- gemm12: h = ELU(A1 @ W1t^T + b1) in LDS; gx2e = h @ G2pT^T ----
__global__ __launch_bounds__(256) void gemm12_kernel(
    const ushort* __restrict__ A1, const ushort* __restrict__ W1t,
    const float* __restrict__ b1, const ushort* __restrict__ G2pT,
    ushort* __restrict__ gx2e, int N) {
  __shared__ __align__(16) ushort As[2][64 * ABST];
  __shared__ __align__(16) ushort Bs[2][64 * ABST];
  __shared__ __align__(16) ushort Hs[64][72];   // padded: no bank wall
  const int t = threadIdx.x, lane = t & 63, wv = t >> 6;
  const int mfrag = lane & 15, quad = lane >> 4;
  const int m0 = (int)blockIdx.x * 64;
  const int st_r = t >> 2, st_c = (t & 3) * 8;
  const int st_o = st_r * ABST + st_c;
  const ushort* ag = A1 + (size_t)(m0 + st_r) * 1152 + st_c;
  const ushort* bg = W1t + (size_t)st_r * 1152 + st_c;

  {
    uint4 a0 = *(const uint4*)ag;
    uint4 b0 = *(const uint4*)bg;
    *(uint4*)(&As[0][st_o]) = a0;
    *(uint4*)(&Bs[0][st_o]) = b0;
  }
  __syncthreads();

  v4f acc[4];
  #pragma unroll
  for (int ct = 0; ct < 4; ++ct) acc[ct] = (v4f){0.f, 0.f, 0.f, 0.f};

  for (int kc = 0; kc < 36; ++kc) {
    const int cb = kc & 1, nb = cb ^ 1;
    uint4 an, bn;
    if (kc < 35) {
      an = *(const uint4*)(ag + (kc + 1) * 32);
      bn = *(const uint4*)(bg + (kc + 1) * 32);
    }
    v8bf a = ld_frag(&As[cb][(wv * 16 + mfrag) * ABST + quad * 8]);
    #pragma unroll
    for (int ct = 0; ct < 4; ++ct) {
      v8bf b = ld_frag(&Bs[cb][(ct * 16 + mfrag) * ABST + quad * 8]);
      acc[ct] = __builtin_amdgcn_mfma_f32_16x16x32_bf16(a, b, acc[ct], 0, 0, 0);
    }
    if (kc < 35) {
      *(uint4*)(&As[nb][st_o]) = an;
      *(uint4*)(&Bs[nb][st_o]) = bn;
      __syncthreads();
    }
  }
  // epilogue 1: ELU -> Hs (LDS), no global h round-trip
  #pragma unroll
  for (int ct = 0; ct < 4; ++ct) {
    const int colh = ct * 16 + mfrag;
    const float bc = b1[colh];
    #pragma unroll
    for (int r = 0; r < 4; ++r) {
      float v = acc[ct][r] + bc;
      v = v > 0.f ? v : expm1f(v);
      Hs[wv * 16 + quad * 4 + r][colh] = f2bu(v);
    }
  }
  __syncthreads();

  // phase 2 (was gemm2a): gx2e = Hs @ G2pT^T
  v4f acc2[9];
  #pragma unroll
  for (int t9 = 0; t9 < 9; ++t9) acc2[t9] = (v4f){0.f, 0.f, 0.f, 0.f};
  const ushort* brow = G2pT + (size_t)mfrag * 64 + quad * 8;
  #pragma unroll
  for (int kc = 0; kc < 2; ++kc) {
    v8bf a = ld_frag(&Hs[wv * 16 + mfrag][quad * 8 + kc * 32]);
    #pragma unroll
    for (int t9 = 0; t9 < 9; ++t9) {
      v8bf b = ld_frag(brow + (size_t)t9 * 16 * 64 + kc * 32);
      acc2[t9] = __builtin_amdgcn_mfma_f32_16x16x32_bf16(a, b, acc2[t9], 0, 0, 0);
    }
  }
  #pragma unroll
  for (int t9 = 0; t9 < 9; ++t9) {
    #pragma unroll
    for (int r = 0; r < 4; ++r) {
      int node = m0 + wv * 16 + quad * 4 + r;
      if (node < N)
        gx2e[(size_t)node * GXST + t9 * 16 + mfrag] = f2bu(acc2[t9][r]);
    }
  }
}

// ==== edge2: out = lsm( (sum_e w.gx2e[r])/deg + root + b2 ) ====
// Unpredicated 8-blocks + scalar tail.
__global__ __launch_bounds__(256) void edge2_kernel(
    const ushort* __restrict__ gx2e, const uint2* __restrict__ rec,
    const float* __restrict__ mu2, const float* __restrict__ sg2,
    const int* __restrict__ starts, const float* __restrict__ b2,
    float* __restrict__ out, int N) {
  __shared__ __align__(16) float lw[E2CAP + 8][8];
  __shared__ int loff[E2CAP + 8];
  __shared__ float lb2[16];
  __shared__ float prm[32];
  const int t = threadIdx.x, lane = t & 63, wv = t >> 6;
  const int base = (int)blockIdx.x * E2NODES;
  const int S = starts[base];
  const int cl = min(starts[base + E2NODES] - S, E2CAP);
  if (t < 16) lb2[t] = b2[t];
  if (t < 8) {
    float s0 = sg2[2 * t], s1 = sg2[2 * t + 1];
    prm[t] = -0.5f / (1e-15f + s0 * s0);
    prm[8 + t] = -0.5f / (1e-15f + s1 * s1);
    prm[16 + t] = mu2[2 * t];
    prm[24 + t] = mu2[2 * t + 1];
  }
  __syncthreads();
  for (int i = t; i < cl; i += 256) {
    uint2 rr = rec[S + i];
    loff[i] = (int)rr.x * 320;
    float2 p = unph2(rr.y);
    float w[8];
    #pragma unroll
    for (int k = 0; k < 8; ++k) {
      float d0 = p.x - prm[16 + k], d1 = p.y - prm[24 + k];
      w[k] = __expf(fmaf(d0 * d0, prm[k], d1 * d1 * prm[8 + k]));
    }
    *(float4*)&lw[i][0] = make_float4(w[0], w[1], w[2], w[3]);
    *(float4*)&lw[i][4] = make_float4(w[4], w[5], w[6], w[7]);
  }
  if (t < 8) {                             // 8 zero-weight sentinels (safety)
    loff[cl + t] = 0;
    *(float4*)&lw[cl + t][0] = make_float4(0.f, 0.f, 0.f, 0.f);
    *(float4*)&lw[cl + t][4] = make_float4(0.f, 0.f, 0.f, 0.f);
  }
  __syncthreads();

  const int o = lane & 15, kq = lane >> 4;
  const char* gb = (const char*)gx2e + kq * 64 + o * 4;

  for (int i = 0; i < E2NODES / 4; ++i) {
    const int n = base + wv * 4 + i;
    if (n >= N) continue;
    const int be = starts[n], ee = starts[n + 1];
    v2f ACC = (v2f){0.f, 0.f};
    const int reRel = min(ee - S, cl);
    int q = min(be - S, cl);
    for (; q + 8 <= reRel; q += 8) {       // full blocks: no predication
      int off[8];
      #pragma unroll
      for (int u = 0; u < 8; ++u) off[u] = loff[q + u];
      uint g[8];
      #pragma unroll
      for (int u = 0; u < 8; ++u) g[u] = *(const uint*)(gb + off[u]);
      #pragma unroll
      for (int u = 0; u < 8; ++u) {
        v2f W = *(v2f*)&lw[q + u][kq * 2];
        v2f F;
        F.x = __uint_as_float(g[u] << 16);
        F.y = __uint_as_float(g[u] & 0xffff0000u);
        ACC = __builtin_elementwise_fma(W, F, ACC);
      }
    }
    for (; q < reRel; ++q) {               // scalar tail (<8 edges)
      uint g = *(const uint*)(gb + loff[q]);
      v2f W = *(v2f*)&lw[q][kq * 2];
      v2f F;
      F.x = __uint_as_float(g << 16);
      F.y = __uint_as_float(g & 0xffff0000u);
      ACC = __builtin_elementwise_fma(W, F, ACC);
    }
    float s = ACC.x + ACC.y;
    s += __shfl_xor(s, 16, 64);
    s += __shfl_xor(s, 32, 64);
    const float inv = 1.f / fmaxf((float)(ee - be), 1.f);
    ushort ru = *((const ushort*)gx2e + (size_t)n * GXST + 128 + o);
    float root = __uint_as_float(((uint)ru) << 16);
    float v = s * inv + root + lb2[o];
    float mx = v;
    #pragma unroll
    for (int off = 8; off >= 1; off >>= 1) mx = fmaxf(mx, __shfl_xor(mx, off, 64));
    float sm = __expf(v - mx);
    #pragma unroll
    for (int off = 8; off >= 1; off >>= 1) sm += __shfl_xor(sm, off, 64);
    if (kq == 0) out[(size_t)n * NC + o] = v - mx - __logf(sm);
  }
}

extern "C" void kernel_launch(void* const* d_in, const int* in_sizes, int n_in,
                              void* d_out, int out_size, void* d_ws, size_t ws_size,
                              hipStream_t stream) {
  const float* x     = (const float*)d_in[0];
  const int*   eidx  = (const int*)d_in[1];
  const float* eattr = (const float*)d_in[2];
  const float* g1w   = (const float*)d_in[3];
  const float* mu1   = (const float*)d_in[4];
  const float* sg1   = (const float*)d_in[5];
  const float* r1w   = (const float*)d_in[6];
  const float* b1    = (const float*)d_in[7];
  const float* g2w   = (const float*)d_in[8];
  const float* mu2   = (const float*)d_in[9];
  const float* sg2   = (const float*)d_in[10];
  const float* r2w   = (const float*)d_in[11];
  const float* b2    = (const float*)d_in[12];

  const int N = in_sizes[0] / NF;        // 50000
  const int E = in_sizes[1] / 2;         // 800000
  const int* row = eidx;
  const int* col = eidx + E;
  const int N2 = (N + 63) & ~63;         // 50048
  const int NP = (N + 1023) & ~1023;     // 50176
  const int NB = NP / 1024;              // 49 (must be <= 64 for scan_kernel)

  // layout: [rec | gx2e | A1 | W1t | G2pT | rc | counts | starts | bagg]
  char* wsb = (char*)d_ws;
  uint2* rec   = (uint2*)wsb;                              // E*8B (live to end)
  ushort* gx2e = (ushort*)(wsb + (size_t)E * 8);           // N2*320B
  ushort* A1   = gx2e + (size_t)N2 * GXST;                 // N2*1152 (Z1|x)
  ushort* W1t  = A1 + (size_t)N2 * 1152;                   // 64*1152
  ushort* G2pT = W1t + (size_t)64 * 1152;                  // 144*64
  int* rc      = (int*)(G2pT + (size_t)144 * 64);          // E
  int* counts  = rc + (size_t)E;                           // NP
  int* starts  = counts + NP;                              // NP
  int* bagg    = starts + NP;                              // 64

  const int bh = (E + 255) / 256;
  const int bc = (N * 32 + 255) / 256;
  const int bp = (64 * 1152 + 144 * 64 + 255) / 256;

  hipMemsetAsync(counts, 0, (size_t)NP * sizeof(int), stream);
  setup_kernel<<<bh + bc + bp + 1, 256, 0, stream>>>(
      col, x, g1w, r1w, g2w, r2w, counts, rc, A1, W1t, G2pT, bagg,
      E, N, bh, bc, bp);
  scan_kernel<<<NB, 256, 0, stream>>>(counts, starts, bagg, NB);
  fillrec_kernel<<<bh, 256, 0, stream>>>(row, rc, starts, eattr, rec, E);
  z1_kernel<<<N / Z1NODES, 256, 0, stream>>>(A1, rec, mu1, sg1, starts, N);
  gemm12_kernel<<<N2 / 64, 256, 0, stream>>>(A1, W1t, b1, G2pT, gx2e, N);
  edge2_kernel<<<(N + E2NODES - 1) / E2NODES, 256, 0, stream>>>(
      gx2e, rec, mu2, sg2, starts, b2, (float*)d_out, N);
}